// Round 8
// baseline (118.633 us; speedup 1.0000x reference)
//
#include <hip/hip_runtime.h>
#include <hip/hip_bf16.h>
#include <math.h>

#define NUM_CLASSES 124
#define NCLS_PAD    128
#define FEAT_CH     64
#define OUT_HW      480
#define IN_HW       120
#define NPIX        (OUT_HW * OUT_HW)
#define NCELL       (IN_HW * IN_HW)
#define NCHUNK      (NPIX / 32)         // 7200 chunks of 32 px (15 per row)
#define EPSV        1e-8f

#define STRIDE_ACC   65
#define ACC_FLOATS   (NCLS_PAD * STRIDE_ACC)           // 8320
#define ACC_TOTAL    (ACC_FLOATS + NCLS_PAD)           // 8448

#define STRIDE_MN    65                 // LDS mn row stride (bank spread)
#define MN_FLOATS    (NUM_CLASSES * STRIDE_MN)         // 8060

// ws layout (floats): mn[7936] | fT[14400*64] | part[nb*8448]
#define WS_MN   0
#define WS_FT   (NUM_CLASSES * FEAT_CH)
#define WS_PART (WS_FT + NCELL * FEAT_CH)

#define NTILE   (NCELL / 64)            // 225 transpose tiles

typedef short  v8s __attribute__((ext_vector_type(8)));
typedef float  v4f __attribute__((ext_vector_type(4)));

__device__ __forceinline__ short f2bf(float x) {
    __hip_bfloat16 h = __float2bfloat16(x);
    return __builtin_bit_cast(short, h);
}

// ---- phase 0 (fused): normalize memory, LDS-tiled transpose ------------------
__global__ __launch_bounds__(256) void k_prep(
        const float* __restrict__ mem, const float* __restrict__ feats,
        float* __restrict__ mn, float* __restrict__ fT) {
    const int b = blockIdx.x;
    if (b < NUM_CLASSES) {
        if (threadIdx.x < FEAT_CH) {
            const int c = b, k = threadIdx.x;
            float v = mem[c * FEAT_CH + k];
            float s = v * v;
#pragma unroll
            for (int off = 32; off; off >>= 1) s += __shfl_xor(s, off);
            mn[c * FEAT_CH + k] = v / fmaxf(sqrtf(s), EPSV);
        }
    } else {
        __shared__ float tileL[64 * 65];
        const int t = b - NUM_CLASSES;             // 0..224
        const int q0 = t * 64;
        const int tid = threadIdx.x;
#pragma unroll
        for (int i = 0; i < 16; ++i) {
            const int idx = i * 256 + tid;
            const int k = idx >> 6, q = idx & 63;  // q fast -> coalesced read
            tileL[q * 65 + k] = feats[k * NCELL + q0 + q];
        }
        __syncthreads();
#pragma unroll
        for (int i = 0; i < 16; ++i) {
            const int idx = i * 256 + tid;
            const int q = idx >> 6, k = idx & 63;  // k fast -> coalesced write
            fT[(q0 + q) * FEAT_CH + k] = tileL[q * 65 + k];
        }
    }
}

// ---- DPP rotational butterfly: all-lanes sum within rows of 16 ---------------
template <int CTRL>
__device__ __forceinline__ float dpp_ror_add(float x) {
    int v = __builtin_amdgcn_update_dpp(0, __float_as_int(x), CTRL, 0xF, 0xF, false);
    return x + __int_as_float(v);
}
__device__ __forceinline__ void reduce16_pair(float& a, float& b) {
    a = dpp_ror_add<0x128>(a); b = dpp_ror_add<0x128>(b);   // row_ror:8
    a = dpp_ror_add<0x124>(a); b = dpp_ror_add<0x124>(b);   // row_ror:4
    a = dpp_ror_add<0x122>(a); b = dpp_ror_add<0x122>(b);   // row_ror:2
    a = dpp_ror_add<0x121>(a); b = dpp_ror_add<0x121>(b);   // row_ror:1
}

// ---- phase 1: one-hot MFMA accumulation --------------------------------------
// Round-7 body (zero-spill, select-free) + two latency-chain cuts:
// (a) seg software pipeline: next chunk's two int4 loads issue before the
//     current chunk's compute -> the L2 seg latency (head of the
//     seg->mn->dt chain) leaves the steady-state critical path. +8 VGPR.
// (b) mn staged in LDS (stride 65): the per-chunk 32-access random-row
//     gather drops from ~200cyc global to LDS latency; banking ~2-way
//     (row of 16 lanes reads 16 consecutive words = 16 distinct banks).
// Occupancy is pinned at 2 waves/SIMD by the 128-AGPR accumulator, so
// in-wave latency cuts are the only available lever.
// Spill gate: k_accum WRITE_SIZE must stay == part size (~8.7 MB).
__global__ __launch_bounds__(512, 2) void k_accum(
        const float* __restrict__ fT, const int* __restrict__ seg,
        const float* __restrict__ mn, float* __restrict__ part) {
    __shared__ float accL[ACC_FLOATS];
    __shared__ float cntL[NCLS_PAD];
    __shared__ float mnL[MN_FLOATS];

    const int tid = threadIdx.x;
    for (int i = tid; i < ACC_FLOATS; i += 512) accL[i] = 0.0f;
    if (tid < NCLS_PAD) cntL[tid] = 0.0f;
    for (int i = tid; i < MN_FLOATS; i += 512) {
        const int c = i / STRIDE_MN, k = i - c * STRIDE_MN;
        mnL[i] = (k < FEAT_CH) ? mn[c * FEAT_CH + k] : 0.0f;
    }
    __syncthreads();

    const int lane = tid & 63;
    const int n  = lane & 15;         // ch within tile / class within band
    const int kg = lane >> 4;         // pixel-group (8 px each)
    const int widx = tid >> 6;        // wave in block (0..7)
    const int gwave = blockIdx.x * 8 + widx;
    const int nw = gridDim.x * 8;

    v4f acc[8][4];
#pragma unroll
    for (int b = 0; b < 8; ++b)
#pragma unroll
        for (int t = 0; t < 4; ++t) acc[b][t] = (v4f)0.0f;

    int ch = gwave;
    int4 ps0, ps1;                    // pipelined seg regs
    if (ch < NCHUNK) {
        const int oy = ch / 15;
        const int px = (ch - oy * 15) * 32 + kg * 8;
        const int4* sp = (const int4*)(seg + oy * OUT_HW + px);
        ps0 = sp[0]; ps1 = sp[1];
    }

    while (ch < NCHUNK) {
        const int oy  = ch / 15;
        const int px0 = (ch - oy * 15) * 32 + kg * 8;   // my first ox
        const int chn_next = ch + nw;

        int segj[8];
        segj[0]=ps0.x; segj[1]=ps0.y; segj[2]=ps0.z; segj[3]=ps0.w;
        segj[4]=ps1.x; segj[5]=ps1.y; segj[6]=ps1.z; segj[7]=ps1.w;

        // issue next chunk's seg loads NOW (hidden under this chunk's compute)
        if (chn_next < NCHUNK) {
            const int oy2 = chn_next / 15;
            const int px2 = (chn_next - oy2 * 15) * 32 + kg * 8;
            const int4* sp2 = (const int4*)(seg + oy2 * OUT_HW + px2);
            ps0 = sp2[0]; ps1 = sp2[1];
        }

        float fy = fminf(fmaxf(oy * 0.25f - 0.375f, 0.0f), 119.0f);
        const int y0 = (int)fy; const float ty = fy - (float)y0;
        const int y1 = min(y0 + 1, IN_HW - 1);
        const int base = px0 >> 2;                       // integer (px0 % 8 == 0)
        const int c0 = max(base - 1, 0), c1 = base;
        const int c2 = min(base + 1, IN_HW - 1), c3 = min(base + 2, IN_HW - 1);
        const int r0 = y0 * IN_HW, r1 = y1 * IN_HW;

        float nr[8], dt[8];
#pragma unroll
        for (int j = 0; j < 8; ++j) { nr[j] = 0.0f; dt[j] = 0.0f; }
        v8s Bfrag[4];
#pragma unroll
        for (int t = 0; t < 4; ++t) {
            const int chn = n + 16 * t;
            const float T0 = fT[(r0+c0)*64+chn], T1 = fT[(r0+c1)*64+chn];
            const float T2 = fT[(r0+c2)*64+chn], T3 = fT[(r0+c3)*64+chn];
            const float B0 = fT[(r1+c0)*64+chn], B1 = fT[(r1+c1)*64+chn];
            const float B2 = fT[(r1+c2)*64+chn], B3 = fT[(r1+c3)*64+chn];
#define PXI(J, TX, TL, TR, BL, BR) { \
            float top = fmaf(TX, TR - TL, TL); \
            float bot = fmaf(TX, BR - BL, BL); \
            float v   = fmaf(ty, bot - top, top); \
            nr[J] = fmaf(v, v, nr[J]); \
            dt[J] = fmaf(v, mnL[segj[J] * STRIDE_MN + chn], dt[J]); \
            Bfrag[t][J] = f2bf(v); }
            PXI(0, 0.625f, T0, T1, B0, B1)
            PXI(1, 0.875f, T0, T1, B0, B1)
            PXI(2, 0.125f, T1, T2, B1, B2)
            PXI(3, 0.375f, T1, T2, B1, B2)
            PXI(4, 0.625f, T1, T2, B1, B2)
            PXI(5, 0.875f, T1, T2, B1, B2)
            PXI(6, 0.125f, T2, T3, B2, B3)
            PXI(7, 0.375f, T2, T3, B2, B3)
#undef PXI
        }
        // per-pixel reduce over 16 ch-lanes (within the kg row of 16)
#pragma unroll
        for (int j = 0; j < 8; ++j) reduce16_pair(nr[j], dt[j]);

        float wj[8]; short wb[8];
#pragma unroll
        for (int j = 0; j < 8; ++j) {
            wj[j] = 1.0f - dt[j] / fmaxf(sqrtf(nr[j]), EPSV);  // mn==0 rows -> w==1
            wb[j] = f2bf(wj[j]);
        }
        // one-hot A per class band, 4 MFMAs each
#pragma unroll
        for (int b = 0; b < 8; ++b) {
            v8s A;
#pragma unroll
            for (int j = 0; j < 8; ++j)
                A[j] = (segj[j] == b * 16 + n) ? wb[j] : (short)0;
#pragma unroll
            for (int t = 0; t < 4; ++t)
                acc[b][t] = __builtin_amdgcn_mfma_f32_16x16x32_bf16(A, Bfrag[t], acc[b][t], 0, 0, 0);
        }
        // wsum / count (2 LDS atomics per pixel, lanes n==0 only)
        if (n == 0) {
#pragma unroll
            for (int j = 0; j < 8; ++j) {
                atomicAdd(&accL[segj[j] * STRIDE_ACC + FEAT_CH], wj[j]);
                atomicAdd(&cntL[segj[j]], 1.0f);
            }
        }
        ch = chn_next;
    }

    // merge per-wave C into accL (waves sequential; once per block)
    for (int wv = 0; wv < 8; ++wv) {
        __syncthreads();
        if (widx == wv) {
#pragma unroll
            for (int b = 0; b < 8; ++b)
#pragma unroll
                for (int t = 0; t < 4; ++t)
#pragma unroll
                    for (int r = 0; r < 4; ++r) {
                        const int cls = b * 16 + kg * 4 + r;   // C row
                        const int chn = t * 16 + n;            // C col
                        accL[cls * STRIDE_ACC + chn] += acc[b][t][r];
                    }
        }
    }
    __syncthreads();

    float* __restrict__ dst = part + (size_t)blockIdx.x * ACC_TOTAL;
    for (int i = tid; i < ACC_FLOATS; i += 512) dst[i] = accL[i];
    if (tid < NCLS_PAD) dst[ACC_FLOATS + tid] = cntL[tid];
}

// ---- phase 2 (fused reduce + final): one block per class ---------------------
// 124 blocks x 256 thr; group g (of 4) sums parts b = g, g+4, ... with 256 B
// coalesced row segments; LDS combine; first wave applies momentum selects.
// (Proven correct in rounds 4-7.)
__global__ __launch_bounds__(256) void k_final(
        const float* __restrict__ part, const float* __restrict__ mem,
        float* __restrict__ out, int nb) {
    __shared__ float aL[4][FEAT_CH];
    __shared__ float wL[4], cL[4];
    const int c = blockIdx.x;
    const int k = threadIdx.x & 63, g = threadIdx.x >> 6;
    float a = 0.0f, w = 0.0f, cn = 0.0f;
    for (int b = g; b < nb; b += 4) {
        const float* p = part + (size_t)b * ACC_TOTAL;
        a += p[c * STRIDE_ACC + k];
        if (k == 0) { w += p[c * STRIDE_ACC + FEAT_CH]; cn += p[ACC_FLOATS + c]; }
    }
    aL[g][k] = a;
    if (k == 0) { wL[g] = w; cL[g] = cn; }
    __syncthreads();
    if (threadIdx.x < FEAT_CH) {
        const int kk = threadIdx.x;
        const float as = aL[0][kk] + aL[1][kk] + aL[2][kk] + aL[3][kk];
        const float ws = wL[0] + wL[1] + wL[2] + wL[3];
        const float cs = cL[0] + cL[1] + cL[2] + cL[3];
        const float m = mem[c * FEAT_CH + kk];
        const int is_zero = __all(m == 0.0f);        // first wave: 64 lanes = class row
        const float divisor = (ws > 0.0f) ? ws : 1.0f;
        const float val = as / divisor;
        const float nw2 = is_zero ? val : fmaf(0.1f, val, 0.9f * m);
        out[c * FEAT_CH + kk] = (cs > 0.0f) ? nw2 : m;
    }
}

extern "C" void kernel_launch(void* const* d_in, const int* in_sizes, int n_in,
                              void* d_out, int out_size, void* d_ws, size_t ws_size,
                              hipStream_t stream) {
    const float* feats  = (const float*)d_in[0];   // (1,64,120,120) f32
    const float* memory = (const float*)d_in[1];   // (124,1,64) f32
    const int*   seg    = (const int*)d_in[2];     // (1,480,480) i32
    float* out = (float*)d_out;                    // (124,1,64) f32
    float* ws  = (float*)d_ws;

    float* mn   = ws + WS_MN;
    float* fT   = ws + WS_FT;
    float* part = ws + WS_PART;

    long long avail = (long long)(ws_size / 4) - WS_PART;
    const int nb = (avail >= (long long)256 * ACC_TOTAL) ? 256 : 128;

    k_prep<<<NUM_CLASSES + NTILE, 256, 0, stream>>>(memory, feats, mn, fT);
    k_accum<<<nb, 512, 0, stream>>>(fT, seg, mn, part);
    k_final<<<NUM_CLASSES, 256, 0, stream>>>(part, memory, out, nb);
}

// Round 9
// 115.602 us; speedup vs baseline: 1.0262x; 1.0262x over previous
//
#include <hip/hip_runtime.h>
#include <hip/hip_bf16.h>
#include <math.h>

#define NUM_CLASSES 124
#define NCLS_PAD    128
#define FEAT_CH     64
#define OUT_HW      480
#define IN_HW       120
#define NPIX        (OUT_HW * OUT_HW)
#define NCELL       (IN_HW * IN_HW)
#define NCHUNK      (NPIX / 32)         // 7200 chunks of 32 px (15 per row)
#define EPSV        1e-8f

#define STRIDE_ACC   65
#define ACC_FLOATS   (NCLS_PAD * STRIDE_ACC)           // 8320
#define ACC_TOTAL    (ACC_FLOATS + NCLS_PAD)           // 8448

// ws layout (floats): mn[7936] | fT[14400*64] | part[nb*8448]
#define WS_MN   0
#define WS_FT   (NUM_CLASSES * FEAT_CH)
#define WS_PART (WS_FT + NCELL * FEAT_CH)

#define NTILE   (NCELL / 64)            // 225 transpose tiles

typedef short  v8s __attribute__((ext_vector_type(8)));
typedef float  v4f __attribute__((ext_vector_type(4)));

__device__ __forceinline__ short f2bf(float x) {
    __hip_bfloat16 h = __float2bfloat16(x);
    return __builtin_bit_cast(short, h);
}

// ---- phase 0 (fused): normalize memory, LDS-tiled transpose ------------------
__global__ __launch_bounds__(256) void k_prep(
        const float* __restrict__ mem, const float* __restrict__ feats,
        float* __restrict__ mn, float* __restrict__ fT) {
    const int b = blockIdx.x;
    if (b < NUM_CLASSES) {
        if (threadIdx.x < FEAT_CH) {
            const int c = b, k = threadIdx.x;
            float v = mem[c * FEAT_CH + k];
            float s = v * v;
#pragma unroll
            for (int off = 32; off; off >>= 1) s += __shfl_xor(s, off);
            mn[c * FEAT_CH + k] = v / fmaxf(sqrtf(s), EPSV);
        }
    } else {
        __shared__ float tileL[64 * 65];
        const int t = b - NUM_CLASSES;             // 0..224
        const int q0 = t * 64;
        const int tid = threadIdx.x;
#pragma unroll
        for (int i = 0; i < 16; ++i) {
            const int idx = i * 256 + tid;
            const int k = idx >> 6, q = idx & 63;  // q fast -> coalesced read
            tileL[q * 65 + k] = feats[k * NCELL + q0 + q];
        }
        __syncthreads();
#pragma unroll
        for (int i = 0; i < 16; ++i) {
            const int idx = i * 256 + tid;
            const int q = idx >> 6, k = idx & 63;  // k fast -> coalesced write
            fT[(q0 + q) * FEAT_CH + k] = tileL[q * 65 + k];
        }
    }
}

// ---- DPP rotational butterfly: all-lanes sum within rows of 16 ---------------
template <int CTRL>
__device__ __forceinline__ float dpp_ror_add(float x) {
    int v = __builtin_amdgcn_update_dpp(0, __float_as_int(x), CTRL, 0xF, 0xF, false);
    return x + __int_as_float(v);
}
__device__ __forceinline__ void reduce16_pair(float& a, float& b) {
    a = dpp_ror_add<0x128>(a); b = dpp_ror_add<0x128>(b);   // row_ror:8
    a = dpp_ror_add<0x124>(a); b = dpp_ror_add<0x124>(b);   // row_ror:4
    a = dpp_ror_add<0x122>(a); b = dpp_ror_add<0x122>(b);   // row_ror:2
    a = dpp_ror_add<0x121>(a); b = dpp_ror_add<0x121>(b);   // row_ror:1
}

// ---- phase 1: one-hot MFMA accumulation --------------------------------------
// Round-7 body (zero-spill, select-free — the measured best at 115.7 us) with
// ONE change: grid-stride (stride 2048, zero fT row reuse: oy jumps ~136 rows
// per wave-iteration) -> contiguous per-wave chunk ranges. A wave's 3-4 chunks
// now share the same output row oy (15 chunks/row), so the fT rows r0/r1 stay
// L1-hot across its iterations and seg reads are sequential. Range bounds are
// two scalar regs; per-lane register pressure is untouched.
// Round-8 lesson: seg software-pipeline + mn-in-LDS were neutral (-3 us) ->
// reverted; the stall is the fT re-fetch chain, not the seg/mn gathers.
// Spill gate: k_accum WRITE_SIZE must stay == part size (~8.7 MB); total must
// not regress past 120 us, else revert to round-7 verbatim.
__global__ __launch_bounds__(512, 2) void k_accum(
        const float* __restrict__ fT, const int* __restrict__ seg,
        const float* __restrict__ mn, float* __restrict__ part) {
    __shared__ float accL[ACC_FLOATS];
    __shared__ float cntL[NCLS_PAD];

    const int tid = threadIdx.x;
    for (int i = tid; i < ACC_FLOATS; i += 512) accL[i] = 0.0f;
    if (tid < NCLS_PAD) cntL[tid] = 0.0f;
    __syncthreads();

    const int lane = tid & 63;
    const int n  = lane & 15;         // ch within tile / class within band
    const int kg = lane >> 4;         // pixel-group (8 px each)
    const int widx = tid >> 6;        // wave in block (0..7)
    const int gwave = blockIdx.x * 8 + widx;
    const int nw = gridDim.x * 8;

    v4f acc[8][4];
#pragma unroll
    for (int b = 0; b < 8; ++b)
#pragma unroll
        for (int t = 0; t < 4; ++t) acc[b][t] = (v4f)0.0f;

    const int chA = (int)(((long long)gwave * NCHUNK) / nw);
    const int chB = (int)(((long long)(gwave + 1) * NCHUNK) / nw);

    for (int ch = chA; ch < chB; ++ch) {
        const int oy  = ch / 15;
        const int px0 = (ch - oy * 15) * 32 + kg * 8;   // my first ox
        float fy = fminf(fmaxf(oy * 0.25f - 0.375f, 0.0f), 119.0f);
        const int y0 = (int)fy; const float ty = fy - (float)y0;
        const int y1 = min(y0 + 1, IN_HW - 1);
        const int base = px0 >> 2;                       // integer (px0 % 8 == 0)
        const int c0 = max(base - 1, 0), c1 = base;
        const int c2 = min(base + 1, IN_HW - 1), c3 = min(base + 2, IN_HW - 1);
        const int r0 = y0 * IN_HW, r1 = y1 * IN_HW;

        int segj[8];
        {
            const int4* sp = (const int4*)(seg + oy * OUT_HW + px0);
            int4 s0 = sp[0], s1 = sp[1];
            segj[0]=s0.x; segj[1]=s0.y; segj[2]=s0.z; segj[3]=s0.w;
            segj[4]=s1.x; segj[5]=s1.y; segj[6]=s1.z; segj[7]=s1.w;
        }

        float nr[8], dt[8];
#pragma unroll
        for (int j = 0; j < 8; ++j) { nr[j] = 0.0f; dt[j] = 0.0f; }
        v8s Bfrag[4];
#pragma unroll
        for (int t = 0; t < 4; ++t) {
            const int chn = n + 16 * t;
            const float T0 = fT[(r0+c0)*64+chn], T1 = fT[(r0+c1)*64+chn];
            const float T2 = fT[(r0+c2)*64+chn], T3 = fT[(r0+c3)*64+chn];
            const float B0 = fT[(r1+c0)*64+chn], B1 = fT[(r1+c1)*64+chn];
            const float B2 = fT[(r1+c2)*64+chn], B3 = fT[(r1+c3)*64+chn];
#define PXI(J, TX, TL, TR, BL, BR) { \
            float top = fmaf(TX, TR - TL, TL); \
            float bot = fmaf(TX, BR - BL, BL); \
            float v   = fmaf(ty, bot - top, top); \
            nr[J] = fmaf(v, v, nr[J]); \
            dt[J] = fmaf(v, mn[segj[J] * 64 + chn], dt[J]); \
            Bfrag[t][J] = f2bf(v); }
            PXI(0, 0.625f, T0, T1, B0, B1)
            PXI(1, 0.875f, T0, T1, B0, B1)
            PXI(2, 0.125f, T1, T2, B1, B2)
            PXI(3, 0.375f, T1, T2, B1, B2)
            PXI(4, 0.625f, T1, T2, B1, B2)
            PXI(5, 0.875f, T1, T2, B1, B2)
            PXI(6, 0.125f, T2, T3, B2, B3)
            PXI(7, 0.375f, T2, T3, B2, B3)
#undef PXI
        }
        // per-pixel reduce over 16 ch-lanes (within the kg row of 16)
#pragma unroll
        for (int j = 0; j < 8; ++j) reduce16_pair(nr[j], dt[j]);

        float wj[8]; short wb[8];
#pragma unroll
        for (int j = 0; j < 8; ++j) {
            wj[j] = 1.0f - dt[j] / fmaxf(sqrtf(nr[j]), EPSV);  // mn==0 rows -> w==1
            wb[j] = f2bf(wj[j]);
        }
        // one-hot A per class band, 4 MFMAs each
#pragma unroll
        for (int b = 0; b < 8; ++b) {
            v8s A;
#pragma unroll
            for (int j = 0; j < 8; ++j)
                A[j] = (segj[j] == b * 16 + n) ? wb[j] : (short)0;
#pragma unroll
            for (int t = 0; t < 4; ++t)
                acc[b][t] = __builtin_amdgcn_mfma_f32_16x16x32_bf16(A, Bfrag[t], acc[b][t], 0, 0, 0);
        }
        // wsum / count (2 LDS atomics per pixel, lanes n==0 only)
        if (n == 0) {
#pragma unroll
            for (int j = 0; j < 8; ++j) {
                atomicAdd(&accL[segj[j] * STRIDE_ACC + FEAT_CH], wj[j]);
                atomicAdd(&cntL[segj[j]], 1.0f);
            }
        }
    }

    // merge per-wave C into accL (waves sequential; once per block)
    for (int wv = 0; wv < 8; ++wv) {
        __syncthreads();
        if (widx == wv) {
#pragma unroll
            for (int b = 0; b < 8; ++b)
#pragma unroll
                for (int t = 0; t < 4; ++t)
#pragma unroll
                    for (int r = 0; r < 4; ++r) {
                        const int cls = b * 16 + kg * 4 + r;   // C row
                        const int chn = t * 16 + n;            // C col
                        accL[cls * STRIDE_ACC + chn] += acc[b][t][r];
                    }
        }
    }
    __syncthreads();

    float* __restrict__ dst = part + (size_t)blockIdx.x * ACC_TOTAL;
    for (int i = tid; i < ACC_FLOATS; i += 512) dst[i] = accL[i];
    if (tid < NCLS_PAD) dst[ACC_FLOATS + tid] = cntL[tid];
}

// ---- phase 2 (fused reduce + final): one block per class ---------------------
// 124 blocks x 256 thr; group g (of 4) sums parts b = g, g+4, ... with 256 B
// coalesced row segments; LDS combine; first wave applies momentum selects.
// (Proven correct in rounds 4-8.)
__global__ __launch_bounds__(256) void k_final(
        const float* __restrict__ part, const float* __restrict__ mem,
        float* __restrict__ out, int nb) {
    __shared__ float aL[4][FEAT_CH];
    __shared__ float wL[4], cL[4];
    const int c = blockIdx.x;
    const int k = threadIdx.x & 63, g = threadIdx.x >> 6;
    float a = 0.0f, w = 0.0f, cn = 0.0f;
    for (int b = g; b < nb; b += 4) {
        const float* p = part + (size_t)b * ACC_TOTAL;
        a += p[c * STRIDE_ACC + k];
        if (k == 0) { w += p[c * STRIDE_ACC + FEAT_CH]; cn += p[ACC_FLOATS + c]; }
    }
    aL[g][k] = a;
    if (k == 0) { wL[g] = w; cL[g] = cn; }
    __syncthreads();
    if (threadIdx.x < FEAT_CH) {
        const int kk = threadIdx.x;
        const float as = aL[0][kk] + aL[1][kk] + aL[2][kk] + aL[3][kk];
        const float ws = wL[0] + wL[1] + wL[2] + wL[3];
        const float cs = cL[0] + cL[1] + cL[2] + cL[3];
        const float m = mem[c * FEAT_CH + kk];
        const int is_zero = __all(m == 0.0f);        // first wave: 64 lanes = class row
        const float divisor = (ws > 0.0f) ? ws : 1.0f;
        const float val = as / divisor;
        const float nw2 = is_zero ? val : fmaf(0.1f, val, 0.9f * m);
        out[c * FEAT_CH + kk] = (cs > 0.0f) ? nw2 : m;
    }
}

extern "C" void kernel_launch(void* const* d_in, const int* in_sizes, int n_in,
                              void* d_out, int out_size, void* d_ws, size_t ws_size,
                              hipStream_t stream) {
    const float* feats  = (const float*)d_in[0];   // (1,64,120,120) f32
    const float* memory = (const float*)d_in[1];   // (124,1,64) f32
    const int*   seg    = (const int*)d_in[2];     // (1,480,480) i32
    float* out = (float*)d_out;                    // (124,1,64) f32
    float* ws  = (float*)d_ws;

    float* mn   = ws + WS_MN;
    float* fT   = ws + WS_FT;
    float* part = ws + WS_PART;

    long long avail = (long long)(ws_size / 4) - WS_PART;
    const int nb = (avail >= (long long)256 * ACC_TOTAL) ? 256 : 128;

    k_prep<<<NUM_CLASSES + NTILE, 256, 0, stream>>>(memory, feats, mn, fT);
    k_accum<<<nb, 512, 0, stream>>>(fT, seg, mn, part);
    k_final<<<NUM_CLASSES, 256, 0, stream>>>(part, memory, out, nb);
}